// Round 4
// baseline (26.775 us; speedup 1.0000x reference)
//
#include <hip/hip_runtime.h>

// CyclicShiftConv collapse (proven R1-R3, absmax 0.0):
//   Every rot_idx row is a permutation of [0,L) => s[b,c,r] is r-independent
//   => softmax over R=4 equal logits == exactly 0.25 =>
//   out[b,c,l] = 0.25 * (x[b,c,l] + sum_{r=1..3} x[b,c, rot_idx[r,l]]).
//   rot_idx[0] is the identity; w1/b1/w2/b2 are mathematically dead.
//
// R4 structure:
//   * 48 PRE-SHIFTED byte addresses live in VGPRs -> each gather is a single
//     ds_read_b32 (row-1 base folds into the 16-bit offset: immediate).
//     No unpack VALU on the gather path (R3 spent ~2 VALU per read).
//   * r=0 term read back from LDS via linear ds_read_b128 (conflict-free)
//     instead of float4 register caches -> VGPR ~75, 5 blocks/CU.
//   * ROWS=2 staged up-front, ONE __syncthreads per block; block reads a
//     contiguous 32 KiB; 20 waves/CU to overlap LDS-gather vs HBM streams.
//   * Non-temporal stores: out is write-once, keep x L3-resident.

constexpr int L  = 4096;          // N*N
constexpr int NB = (16 * 256) / 2;  // 2048 blocks, 2 rows each

typedef float f4 __attribute__((ext_vector_type(4)));

__global__ __launch_bounds__(256) void rotavg_kernel(
    const float* __restrict__ x,
    const int*   __restrict__ rot,
    float*       __restrict__ out) {
  __shared__ float row[2][L];     // 32 KiB -> 5 blocks/CU

  const int t = threadIdx.x;
  const size_t r0 = (size_t)blockIdx.x * 2;

  // ---- index load: 48 byte-addresses, fully unrolled (stay in VGPRs) ----
  unsigned ad[48];                // [i*12 + r*4 + k]
#pragma unroll
  for (int i = 0; i < 4; ++i) {
#pragma unroll
    for (int r = 0; r < 3; ++r) {
      const int4 v = reinterpret_cast<const int4*>(rot + (r + 1) * L)[t + i * 256];
      ad[i * 12 + r * 4 + 0] = (unsigned)v.x << 2;
      ad[i * 12 + r * 4 + 1] = (unsigned)v.y << 2;
      ad[i * 12 + r * 4 + 2] = (unsigned)v.z << 2;
      ad[i * 12 + r * 4 + 3] = (unsigned)v.w << 2;
    }
  }

  // ---- stage both rows (contiguous 32 KiB read), one barrier ----
  {
    const f4* xs = reinterpret_cast<const f4*>(x + r0 * L);
    f4* s = reinterpret_cast<f4*>(&row[0][0]);
#pragma unroll
    for (int i = 0; i < 8; ++i) s[t + i * 256] = xs[t + i * 256];
  }
  __syncthreads();

  // ---- gather + average, both rows ----
#pragma unroll
  for (int jj = 0; jj < 2; ++jj) {
    const char* base = reinterpret_cast<const char*>(&row[jj][0]);
    f4* o4 = reinterpret_cast<f4*>(out + (r0 + jj) * L);
#pragma unroll
    for (int i = 0; i < 4; ++i) {
      const int e = t + i * 256;
      const f4 own = *reinterpret_cast<const f4*>(base + e * 16);  // identity rot
      f4 v;
#pragma unroll
      for (int k = 0; k < 4; ++k) {
        const float g90  = *reinterpret_cast<const float*>(base + ad[i * 12 + 0 + k]);
        const float g180 = *reinterpret_cast<const float*>(base + ad[i * 12 + 4 + k]);
        const float g270 = *reinterpret_cast<const float*>(base + ad[i * 12 + 8 + k]);
        v[k] = 0.25f * (own[k] + g90 + g180 + g270);
      }
      __builtin_nontemporal_store(v, &o4[e]);
    }
  }
}

extern "C" void kernel_launch(void* const* d_in, const int* in_sizes, int n_in,
                              void* d_out, int out_size, void* d_ws, size_t ws_size,
                              hipStream_t stream) {
  const float* x       = (const float*)d_in[0];
  const int*   rot_idx = (const int*)d_in[1];
  // d_in[2..5] = w1, b1, w2, b2 — mathematically dead (softmax of equal logits).
  float* out = (float*)d_out;

  rotavg_kernel<<<NB, 256, 0, stream>>>(x, rot_idx, out);
}